// Round 1
// baseline (68.035 us; speedup 1.0000x reference)
//
#include <hip/hip_runtime.h>

// Problem constants (from reference)
#define I_FEAT 8192
#define O_FEAT 8192
#define BATCH  1024

// Algebraic reduction: out[r] = dot(x[r], colsum(W)) + sum(b)
// K1 geometry: 8 column-blocks (1024 cols each, float4/thread) x 64 row-splits
#define ROW_SPLITS      64
#define ROWS_PER_SPLIT  (O_FEAT / ROW_SPLITS)   // 128
#define COL_BLOCKS      (I_FEAT / 1024)         // 8

// ---------------- K1: partial column sums of W ----------------
__global__ __launch_bounds__(256) void colsum_partial_kernel(
    const float* __restrict__ W, float* __restrict__ partials) {
  const int cb    = blockIdx.x % COL_BLOCKS;
  const int split = blockIdx.x / COL_BLOCKS;
  const int c     = cb * 1024 + threadIdx.x * 4;

  const float* base = W + (size_t)split * ROWS_PER_SPLIT * I_FEAT + c;

  float4 a0 = {0.f, 0.f, 0.f, 0.f};
  float4 a1 = {0.f, 0.f, 0.f, 0.f};
  float4 a2 = {0.f, 0.f, 0.f, 0.f};
  float4 a3 = {0.f, 0.f, 0.f, 0.f};

  for (int r = 0; r < ROWS_PER_SPLIT; r += 4) {
    float4 v0 = *(const float4*)(base + (size_t)(r + 0) * I_FEAT);
    float4 v1 = *(const float4*)(base + (size_t)(r + 1) * I_FEAT);
    float4 v2 = *(const float4*)(base + (size_t)(r + 2) * I_FEAT);
    float4 v3 = *(const float4*)(base + (size_t)(r + 3) * I_FEAT);
    a0.x += v0.x; a0.y += v0.y; a0.z += v0.z; a0.w += v0.w;
    a1.x += v1.x; a1.y += v1.y; a1.z += v1.z; a1.w += v1.w;
    a2.x += v2.x; a2.y += v2.y; a2.z += v2.z; a2.w += v2.w;
    a3.x += v3.x; a3.y += v3.y; a3.z += v3.z; a3.w += v3.w;
  }

  float4 s;
  s.x = (a0.x + a1.x) + (a2.x + a3.x);
  s.y = (a0.y + a1.y) + (a2.y + a3.y);
  s.z = (a0.z + a1.z) + (a2.z + a3.z);
  s.w = (a0.w + a1.w) + (a2.w + a3.w);
  *(float4*)(partials + (size_t)split * I_FEAT + c) = s;
}

// ---------------- K2: reduce partials -> colsum; block 8 reduces b -> bsum ----
__global__ __launch_bounds__(256) void finalize_colsum_kernel(
    const float* __restrict__ partials, const float* __restrict__ b,
    float* __restrict__ colsum, float* __restrict__ bsum) {
  __shared__ float red[4];
  if (blockIdx.x < COL_BLOCKS) {
    const int c = blockIdx.x * 1024 + threadIdx.x * 4;
    float4 s = {0.f, 0.f, 0.f, 0.f};
    for (int sp = 0; sp < ROW_SPLITS; ++sp) {
      float4 v = *(const float4*)(partials + (size_t)sp * I_FEAT + c);
      s.x += v.x; s.y += v.y; s.z += v.z; s.w += v.w;
    }
    *(float4*)(colsum + c) = s;
  } else {
    float s = 0.f;
    const float4* b4 = (const float4*)b;
    for (int j = threadIdx.x; j < O_FEAT / 4; j += 256) {
      float4 v = b4[j];
      s += (v.x + v.y) + (v.z + v.w);
    }
    #pragma unroll
    for (int off = 32; off; off >>= 1) s += __shfl_down(s, off);
    if ((threadIdx.x & 63) == 0) red[threadIdx.x >> 6] = s;
    __syncthreads();
    if (threadIdx.x == 0) bsum[0] = (red[0] + red[1]) + (red[2] + red[3]);
  }
}

// ---------------- K3: out[row] = dot(x[row], colsum) + bsum ----------------
__global__ __launch_bounds__(256) void rowdot_kernel(
    const float* __restrict__ x, const float* __restrict__ colsum,
    const float* __restrict__ bsum, float* __restrict__ out) {
  __shared__ float red[4];
  const int row = blockIdx.x;
  const float4* xr = (const float4*)(x + (size_t)row * I_FEAT);
  const float4* cs = (const float4*)colsum;

  float s = 0.f;
  for (int j = threadIdx.x; j < I_FEAT / 4; j += 256) {  // 8 iterations
    float4 a = xr[j];
    float4 c = cs[j];
    s += a.x * c.x + a.y * c.y + a.z * c.z + a.w * c.w;
  }
  #pragma unroll
  for (int off = 32; off; off >>= 1) s += __shfl_down(s, off);
  if ((threadIdx.x & 63) == 0) red[threadIdx.x >> 6] = s;
  __syncthreads();
  if (threadIdx.x == 0)
    out[row] = (red[0] + red[1]) + (red[2] + red[3]) + bsum[0];
}

extern "C" void kernel_launch(void* const* d_in, const int* in_sizes, int n_in,
                              void* d_out, int out_size, void* d_ws, size_t ws_size,
                              hipStream_t stream) {
  const float* x = (const float*)d_in[0];  // (1024, 8192)
  const float* W = (const float*)d_in[1];  // (8192, 8192)
  const float* b = (const float*)d_in[2];  // (8192,)
  float* out = (float*)d_out;              // (1024,)

  // ws layout: partials [64][8192] f32 (2 MB) | colsum [8192] f32 | bsum [1] f32
  float* partials = (float*)d_ws;
  float* colsum   = partials + (size_t)ROW_SPLITS * I_FEAT;
  float* bsum     = colsum + I_FEAT;

  colsum_partial_kernel<<<COL_BLOCKS * ROW_SPLITS, 256, 0, stream>>>(W, partials);
  finalize_colsum_kernel<<<COL_BLOCKS + 1, 256, 0, stream>>>(partials, b, colsum, bsum);
  rowdot_kernel<<<BATCH, 256, 0, stream>>>(x, colsum, bsum, out);
}